// Round 1
// baseline (626.517 us; speedup 1.0000x reference)
//
#include <hip/hip_runtime.h>

#define EMBED 128
#define NRBF 8
#define MLP_ROWS 32

__device__ __forceinline__ float silu_f(float x) {
  return x / (1.0f + __expf(-x));
}

// ---------------------------------------------------------------------------
// Stage A: prod = (e_rbf @ W_edge^T) * m_ji ; atomic scatter-add into acc[dst]
// One wave per edge iteration; lane owns channels (2l, 2l+1).
// m_ji read: float2/lane = 512B contiguous per wave (coalesced).
// ---------------------------------------------------------------------------
__global__ __launch_bounds__(256) void edge_scatter_kernel(
    const float* __restrict__ m_ji, const float* __restrict__ e_rbf,
    const int* __restrict__ nbr, const float* __restrict__ W_edge,
    float* __restrict__ acc, int n_edges)
{
  const int lane = threadIdx.x & 63;
  const int wave_id = blockIdx.x * (blockDim.x >> 6) + (threadIdx.x >> 6);
  const int n_waves = gridDim.x * (blockDim.x >> 6);

  // hoist this lane's two W_edge rows into registers (16 floats)
  float w0[NRBF], w1[NRBF];
#pragma unroll
  for (int k = 0; k < NRBF; ++k) {
    w0[k] = W_edge[(2 * lane) * NRBF + k];
    w1[k] = W_edge[(2 * lane + 1) * NRBF + k];
  }

  for (int e = wave_id; e < n_edges; e += n_waves) {
    const int dst = nbr[2 * e];
    const float4* rb = reinterpret_cast<const float4*>(e_rbf + (size_t)e * NRBF);
    const float4 ra = rb[0];
    const float4 rc = rb[1];
    float p0 = w0[0] * ra.x + w0[1] * ra.y + w0[2] * ra.z + w0[3] * ra.w
             + w0[4] * rc.x + w0[5] * rc.y + w0[6] * rc.z + w0[7] * rc.w;
    float p1 = w1[0] * ra.x + w1[1] * ra.y + w1[2] * ra.z + w1[3] * ra.w
             + w1[4] * rc.x + w1[5] * rc.y + w1[6] * rc.z + w1[7] * rc.w;
    const float2 m = reinterpret_cast<const float2*>(m_ji + (size_t)e * EMBED)[lane];
    float* d = acc + (size_t)dst * EMBED + 2 * lane;
    atomicAdd(d,     p0 * m.x);
    atomicAdd(d + 1, p1 * m.y);
  }
}

// ---------------------------------------------------------------------------
// Stage B: fused 4-layer MLP. x tile (32 rows x 128) resident in LDS; each
// layer's W staged in LDS in two 32KB half-K chunks (stay < 64KB/block).
// W stored row-major as float4 with XOR swizzle on the k4 slot so that the
// per-lane distinct-c reads spread across 8 distinct 16B bank slots.
// Each thread computes a 4-row x 4-col register tile.
// ---------------------------------------------------------------------------
__global__ __launch_bounds__(256) void mlp_kernel(
    const float* __restrict__ acc,
    const float* __restrict__ W1, const float* __restrict__ b1,
    const float* __restrict__ W2, const float* __restrict__ b2,
    const float* __restrict__ W3, const float* __restrict__ b3,
    const float* __restrict__ Wf,
    float* __restrict__ out, int num_atoms)
{
  __shared__ float4 wlds[128 * 16];      // 32 KB: half-K of one weight matrix
  __shared__ float  xb[MLP_ROWS * 128];  // 16 KB: activation tile

  const int t = threadIdx.x;
  const int rbase = blockIdx.x * MLP_ROWS;

  // load activation tile (guard tail rows with zeros)
  {
    const float4* g = reinterpret_cast<const float4*>(acc);
    float4* x4 = reinterpret_cast<float4*>(xb);
#pragma unroll
    for (int it = 0; it < (MLP_ROWS * 32) / 256; ++it) {
      int i4 = t + it * 256;
      int r = i4 >> 5;
      int grow = rbase + r;
      float4 v = {0.f, 0.f, 0.f, 0.f};
      if (grow < num_atoms) v = g[(size_t)grow * 32 + (i4 & 31)];
      x4[i4] = v;
    }
  }

  const float* Ws[4] = {W1, W2, W3, Wf};
  const float* bs[4] = {b1, b2, b3, nullptr};

  const int c0 = (t & 31) * 4;   // output-channel tile base
  const int r0 = (t >> 5) * 4;   // row tile base

  for (int layer = 0; layer < 4; ++layer) {
    float a[4][4];  // [rr][cc]
    const float* bl = bs[layer];
    float4 bv = {0.f, 0.f, 0.f, 0.f};
    if (bl) bv = *reinterpret_cast<const float4*>(bl + c0);
#pragma unroll
    for (int rr = 0; rr < 4; ++rr) {
      a[rr][0] = bv.x; a[rr][1] = bv.y; a[rr][2] = bv.z; a[rr][3] = bv.w;
    }

    for (int half = 0; half < 2; ++half) {
      // stage this half of W: rows c, k4 in [half*16, half*16+16)
      __syncthreads();  // wlds free (prev readers done)
      {
        const float4* g = reinterpret_cast<const float4*>(Ws[layer]);
#pragma unroll
        for (int it = 0; it < 8; ++it) {
          int i = t + it * 256;           // 2048 float4 per half
          int c = i >> 4;
          int k4h = i & 15;
          wlds[c * 16 + (k4h ^ ((c >> 2) & 7))] = g[c * 32 + half * 16 + k4h];
        }
      }
      __syncthreads();

#pragma unroll
      for (int k4h = 0; k4h < 16; ++k4h) {
        const int kf = (half * 16 + k4h) * 4;
        float4 x0 = *reinterpret_cast<const float4*>(&xb[(r0 + 0) * 128 + kf]);
        float4 x1 = *reinterpret_cast<const float4*>(&xb[(r0 + 1) * 128 + kf]);
        float4 x2 = *reinterpret_cast<const float4*>(&xb[(r0 + 2) * 128 + kf]);
        float4 x3 = *reinterpret_cast<const float4*>(&xb[(r0 + 3) * 128 + kf]);
#pragma unroll
        for (int cc = 0; cc < 4; ++cc) {
          const int c = c0 + cc;
          float4 w = wlds[c * 16 + (k4h ^ ((c >> 2) & 7))];
          a[0][cc] += w.x * x0.x + w.y * x0.y + w.z * x0.z + w.w * x0.w;
          a[1][cc] += w.x * x1.x + w.y * x1.y + w.z * x1.z + w.w * x1.w;
          a[2][cc] += w.x * x2.x + w.y * x2.y + w.z * x2.z + w.w * x2.w;
          a[3][cc] += w.x * x3.x + w.y * x3.y + w.z * x3.z + w.w * x3.w;
        }
      }
    }
    __syncthreads();  // done reading xb + wlds for this layer

    if (layer < 3) {
      // silu + write back activations
#pragma unroll
      for (int rr = 0; rr < 4; ++rr) {
        float4 v;
        v.x = silu_f(a[rr][0]);
        v.y = silu_f(a[rr][1]);
        v.z = silu_f(a[rr][2]);
        v.w = silu_f(a[rr][3]);
        *reinterpret_cast<float4*>(&xb[(r0 + rr) * 128 + c0]) = v;
      }
      __syncthreads();
    } else {
      // final store (no bias, no activation)
#pragma unroll
      for (int rr = 0; rr < 4; ++rr) {
        int grow = rbase + r0 + rr;
        if (grow < num_atoms) {
          float4 v = {a[rr][0], a[rr][1], a[rr][2], a[rr][3]};
          *reinterpret_cast<float4*>(&out[(size_t)grow * 128 + c0]) = v;
        }
      }
    }
  }
}

extern "C" void kernel_launch(void* const* d_in, const int* in_sizes, int n_in,
                              void* d_out, int out_size, void* d_ws, size_t ws_size,
                              hipStream_t stream) {
  const float* m_ji   = (const float*)d_in[0];
  const float* e_rbf  = (const float*)d_in[1];
  const int*   nbr    = (const int*)d_in[2];
  // d_in[3] = num_atoms scalar (device); derive from out_size instead
  const float* W_edge = (const float*)d_in[4];
  const float* W1 = (const float*)d_in[5];
  const float* b1 = (const float*)d_in[6];
  const float* W2 = (const float*)d_in[7];
  const float* b2 = (const float*)d_in[8];
  const float* W3 = (const float*)d_in[9];
  const float* b3 = (const float*)d_in[10];
  const float* Wf = (const float*)d_in[11];
  float* out = (float*)d_out;
  float* acc = (float*)d_ws;

  const int n_edges   = in_sizes[0] / EMBED;
  const int num_atoms = out_size / EMBED;

  // zero the accumulator every call (ws is poisoned once, never re-poisoned)
  hipMemsetAsync(acc, 0, (size_t)num_atoms * EMBED * sizeof(float), stream);

  edge_scatter_kernel<<<2048, 256, 0, stream>>>(m_ji, e_rbf, nbr, W_edge, acc, n_edges);

  const int mlp_blocks = (num_atoms + MLP_ROWS - 1) / MLP_ROWS;
  mlp_kernel<<<mlp_blocks, 256, 0, stream>>>(acc, W1, b1, W2, b2, W3, b3, Wf,
                                             out, num_atoms);
}

// Round 2
// 304.527 us; speedup vs baseline: 2.0573x; 2.0573x over previous
//
#include <hip/hip_runtime.h>

#define EMBED 128
#define NRBF 8
#define MLP_ROWS 32

__device__ __forceinline__ float silu_f(float x) {
  return x / (1.0f + __expf(-x));
}

// ---------------------------------------------------------------------------
// K1: histogram of destination atoms
// ---------------------------------------------------------------------------
__global__ __launch_bounds__(256) void hist_kernel(
    const int* __restrict__ nbr, unsigned* __restrict__ counts, int n_edges)
{
  int i = blockIdx.x * blockDim.x + threadIdx.x;
  const int stride = gridDim.x * blockDim.x;
  const int2* nb = reinterpret_cast<const int2*>(nbr);
  for (; i < n_edges; i += stride) {
    atomicAdd(&counts[nb[i].x], 1u);
  }
}

// ---------------------------------------------------------------------------
// K2: single-block exclusive scan over bins -> bin_start (+ sentinel), cursor
// ---------------------------------------------------------------------------
__global__ __launch_bounds__(1024) void scan_kernel(
    const unsigned* __restrict__ counts, unsigned* __restrict__ bin_start,
    unsigned* __restrict__ cursor, int num_atoms)
{
  __shared__ unsigned sums[1024];
  const int t = threadIdx.x;
  const int items = (num_atoms + 1023) >> 10;
  const int lo = t * items;
  const int hi = min(lo + items, num_atoms);

  unsigned s = 0;
  for (int i = lo; i < hi; ++i) s += counts[i];
  sums[t] = s;
  __syncthreads();

  // Hillis-Steele inclusive scan over 1024 thread sums
  for (int d = 1; d < 1024; d <<= 1) {
    unsigned v = (t >= d) ? sums[t - d] : 0u;
    __syncthreads();
    sums[t] += v;
    __syncthreads();
  }

  unsigned off = (t == 0) ? 0u : sums[t - 1];
  for (int i = lo; i < hi; ++i) {
    unsigned c = counts[i];
    bin_start[i] = off;
    cursor[i] = off;
    off += c;
  }
  if (t == 1023) bin_start[num_atoms] = sums[1023];
}

// ---------------------------------------------------------------------------
// K3: scatter edge ids into sorted order (counting-sort pass 2)
// ---------------------------------------------------------------------------
__global__ __launch_bounds__(256) void scatter_ids_kernel(
    const int* __restrict__ nbr, unsigned* __restrict__ cursor,
    int* __restrict__ sorted, int n_edges)
{
  int i = blockIdx.x * blockDim.x + threadIdx.x;
  const int stride = gridDim.x * blockDim.x;
  const int2* nb = reinterpret_cast<const int2*>(nbr);
  for (; i < n_edges; i += stride) {
    unsigned pos = atomicAdd(&cursor[nb[i].x], 1u);
    sorted[pos] = i;
  }
}

// ---------------------------------------------------------------------------
// K4: gather-reduce. One wave per atom. Lanes cooperatively read 64 edge ids
// (coalesced), broadcast each via shfl; per edge read 512B m_ji row coalesced
// (float2/lane) + 32B uniform rbf; accumulate in registers; single coalesced
// 512B write per atom. No atomics.
// ---------------------------------------------------------------------------
__global__ __launch_bounds__(256) void gather_kernel(
    const float* __restrict__ m_ji, const float* __restrict__ e_rbf,
    const int* __restrict__ sorted, const unsigned* __restrict__ bin_start,
    const float* __restrict__ W_edge, float* __restrict__ node, int num_atoms)
{
  const int lane = threadIdx.x & 63;
  const int wid = blockIdx.x * (blockDim.x >> 6) + (threadIdx.x >> 6);
  if (wid >= num_atoms) return;

  float w0[NRBF], w1[NRBF];
#pragma unroll
  for (int k = 0; k < NRBF; ++k) {
    w0[k] = W_edge[(2 * lane) * NRBF + k];
    w1[k] = W_edge[(2 * lane + 1) * NRBF + k];
  }

  const int s = (int)bin_start[wid];
  const int e = (int)bin_start[wid + 1];

  float sx = 0.f, sy = 0.f;
  for (int base = s; base < e; base += 64) {
    const int cnt = min(64, e - base);
    const int myeid = (base + lane < e) ? sorted[base + lane] : 0;
#pragma unroll 4
    for (int j = 0; j < cnt; ++j) {
      const int eid = __shfl(myeid, j);
      const float4* rb = reinterpret_cast<const float4*>(e_rbf + (size_t)eid * NRBF);
      const float4 ra = rb[0];
      const float4 rc = rb[1];
      const float2 m = reinterpret_cast<const float2*>(m_ji + (size_t)eid * EMBED)[lane];
      float p0 = w0[0] * ra.x + w0[1] * ra.y + w0[2] * ra.z + w0[3] * ra.w
               + w0[4] * rc.x + w0[5] * rc.y + w0[6] * rc.z + w0[7] * rc.w;
      float p1 = w1[0] * ra.x + w1[1] * ra.y + w1[2] * ra.z + w1[3] * ra.w
               + w1[4] * rc.x + w1[5] * rc.y + w1[6] * rc.z + w1[7] * rc.w;
      sx += p0 * m.x;
      sy += p1 * m.y;
    }
  }
  float2 r = {sx, sy};
  reinterpret_cast<float2*>(node + (size_t)wid * EMBED)[lane] = r;
}

// ---------------------------------------------------------------------------
// Fallback Stage A (round-1 path): atomic scatter, used only if ws too small
// ---------------------------------------------------------------------------
__global__ __launch_bounds__(256) void edge_scatter_kernel(
    const float* __restrict__ m_ji, const float* __restrict__ e_rbf,
    const int* __restrict__ nbr, const float* __restrict__ W_edge,
    float* __restrict__ acc, int n_edges)
{
  const int lane = threadIdx.x & 63;
  const int wave_id = blockIdx.x * (blockDim.x >> 6) + (threadIdx.x >> 6);
  const int n_waves = gridDim.x * (blockDim.x >> 6);

  float w0[NRBF], w1[NRBF];
#pragma unroll
  for (int k = 0; k < NRBF; ++k) {
    w0[k] = W_edge[(2 * lane) * NRBF + k];
    w1[k] = W_edge[(2 * lane + 1) * NRBF + k];
  }

  for (int e = wave_id; e < n_edges; e += n_waves) {
    const int dst = nbr[2 * e];
    const float4* rb = reinterpret_cast<const float4*>(e_rbf + (size_t)e * NRBF);
    const float4 ra = rb[0];
    const float4 rc = rb[1];
    float p0 = w0[0] * ra.x + w0[1] * ra.y + w0[2] * ra.z + w0[3] * ra.w
             + w0[4] * rc.x + w0[5] * rc.y + w0[6] * rc.z + w0[7] * rc.w;
    float p1 = w1[0] * ra.x + w1[1] * ra.y + w1[2] * ra.z + w1[3] * ra.w
             + w1[4] * rc.x + w1[5] * rc.y + w1[6] * rc.z + w1[7] * rc.w;
    const float2 m = reinterpret_cast<const float2*>(m_ji + (size_t)e * EMBED)[lane];
    float* d = acc + (size_t)dst * EMBED + 2 * lane;
    atomicAdd(d,     p0 * m.x);
    atomicAdd(d + 1, p1 * m.y);
  }
}

// ---------------------------------------------------------------------------
// Stage B: fused 4-layer MLP (unchanged from R1)
// ---------------------------------------------------------------------------
__global__ __launch_bounds__(256) void mlp_kernel(
    const float* __restrict__ acc,
    const float* __restrict__ W1, const float* __restrict__ b1,
    const float* __restrict__ W2, const float* __restrict__ b2,
    const float* __restrict__ W3, const float* __restrict__ b3,
    const float* __restrict__ Wf,
    float* __restrict__ out, int num_atoms)
{
  __shared__ float4 wlds[128 * 16];      // 32 KB: half-K of one weight matrix
  __shared__ float  xb[MLP_ROWS * 128];  // 16 KB: activation tile

  const int t = threadIdx.x;
  const int rbase = blockIdx.x * MLP_ROWS;

  {
    const float4* g = reinterpret_cast<const float4*>(acc);
    float4* x4 = reinterpret_cast<float4*>(xb);
#pragma unroll
    for (int it = 0; it < (MLP_ROWS * 32) / 256; ++it) {
      int i4 = t + it * 256;
      int r = i4 >> 5;
      int grow = rbase + r;
      float4 v = {0.f, 0.f, 0.f, 0.f};
      if (grow < num_atoms) v = g[(size_t)grow * 32 + (i4 & 31)];
      x4[i4] = v;
    }
  }

  const float* Ws[4] = {W1, W2, W3, Wf};
  const float* bs[4] = {b1, b2, b3, nullptr};

  const int c0 = (t & 31) * 4;
  const int r0 = (t >> 5) * 4;

  for (int layer = 0; layer < 4; ++layer) {
    float a[4][4];
    const float* bl = bs[layer];
    float4 bv = {0.f, 0.f, 0.f, 0.f};
    if (bl) bv = *reinterpret_cast<const float4*>(bl + c0);
#pragma unroll
    for (int rr = 0; rr < 4; ++rr) {
      a[rr][0] = bv.x; a[rr][1] = bv.y; a[rr][2] = bv.z; a[rr][3] = bv.w;
    }

    for (int half = 0; half < 2; ++half) {
      __syncthreads();
      {
        const float4* g = reinterpret_cast<const float4*>(Ws[layer]);
#pragma unroll
        for (int it = 0; it < 8; ++it) {
          int i = t + it * 256;
          int c = i >> 4;
          int k4h = i & 15;
          wlds[c * 16 + (k4h ^ ((c >> 2) & 7))] = g[c * 32 + half * 16 + k4h];
        }
      }
      __syncthreads();

#pragma unroll
      for (int k4h = 0; k4h < 16; ++k4h) {
        const int kf = (half * 16 + k4h) * 4;
        float4 x0 = *reinterpret_cast<const float4*>(&xb[(r0 + 0) * 128 + kf]);
        float4 x1 = *reinterpret_cast<const float4*>(&xb[(r0 + 1) * 128 + kf]);
        float4 x2 = *reinterpret_cast<const float4*>(&xb[(r0 + 2) * 128 + kf]);
        float4 x3 = *reinterpret_cast<const float4*>(&xb[(r0 + 3) * 128 + kf]);
#pragma unroll
        for (int cc = 0; cc < 4; ++cc) {
          const int c = c0 + cc;
          float4 w = wlds[c * 16 + (k4h ^ ((c >> 2) & 7))];
          a[0][cc] += w.x * x0.x + w.y * x0.y + w.z * x0.z + w.w * x0.w;
          a[1][cc] += w.x * x1.x + w.y * x1.y + w.z * x1.z + w.w * x1.w;
          a[2][cc] += w.x * x2.x + w.y * x2.y + w.z * x2.z + w.w * x2.w;
          a[3][cc] += w.x * x3.x + w.y * x3.y + w.z * x3.z + w.w * x3.w;
        }
      }
    }
    __syncthreads();

    if (layer < 3) {
#pragma unroll
      for (int rr = 0; rr < 4; ++rr) {
        float4 v;
        v.x = silu_f(a[rr][0]);
        v.y = silu_f(a[rr][1]);
        v.z = silu_f(a[rr][2]);
        v.w = silu_f(a[rr][3]);
        *reinterpret_cast<float4*>(&xb[(r0 + rr) * 128 + c0]) = v;
      }
      __syncthreads();
    } else {
#pragma unroll
      for (int rr = 0; rr < 4; ++rr) {
        int grow = rbase + r0 + rr;
        if (grow < num_atoms) {
          float4 v = {a[rr][0], a[rr][1], a[rr][2], a[rr][3]};
          *reinterpret_cast<float4*>(&out[(size_t)grow * 128 + c0]) = v;
        }
      }
    }
  }
}

extern "C" void kernel_launch(void* const* d_in, const int* in_sizes, int n_in,
                              void* d_out, int out_size, void* d_ws, size_t ws_size,
                              hipStream_t stream) {
  const float* m_ji   = (const float*)d_in[0];
  const float* e_rbf  = (const float*)d_in[1];
  const int*   nbr    = (const int*)d_in[2];
  const float* W_edge = (const float*)d_in[4];
  const float* W1 = (const float*)d_in[5];
  const float* b1 = (const float*)d_in[6];
  const float* W2 = (const float*)d_in[7];
  const float* b2 = (const float*)d_in[8];
  const float* W3 = (const float*)d_in[9];
  const float* b3 = (const float*)d_in[10];
  const float* Wf = (const float*)d_in[11];
  float* out = (float*)d_out;

  const int n_edges   = in_sizes[0] / EMBED;
  const int num_atoms = out_size / EMBED;

  // workspace layout
  char* p = (char*)d_ws;
  float* node = (float*)p;                 p += (size_t)num_atoms * EMBED * sizeof(float);
  unsigned* counts    = (unsigned*)p;      p += (size_t)num_atoms * sizeof(unsigned);
  unsigned* bin_start = (unsigned*)p;      p += (size_t)(num_atoms + 1) * sizeof(unsigned);
  unsigned* cursor    = (unsigned*)p;      p += (size_t)num_atoms * sizeof(unsigned);
  int* sorted         = (int*)p;           p += (size_t)n_edges * sizeof(int);
  const size_t need = (size_t)(p - (char*)d_ws);

  if (ws_size >= need) {
    // counting-sort + gather path (no heavy atomics)
    hipMemsetAsync(counts, 0, (size_t)num_atoms * sizeof(unsigned), stream);
    hist_kernel<<<1024, 256, 0, stream>>>(nbr, counts, n_edges);
    scan_kernel<<<1, 1024, 0, stream>>>(counts, bin_start, cursor, num_atoms);
    scatter_ids_kernel<<<1024, 256, 0, stream>>>(nbr, cursor, sorted, n_edges);
    const int gblocks = (num_atoms + 3) / 4;  // 4 waves (atoms) per block
    gather_kernel<<<gblocks, 256, 0, stream>>>(m_ji, e_rbf, sorted, bin_start,
                                               W_edge, node, num_atoms);
  } else {
    // fallback: atomic scatter
    hipMemsetAsync(node, 0, (size_t)num_atoms * EMBED * sizeof(float), stream);
    edge_scatter_kernel<<<2048, 256, 0, stream>>>(m_ji, e_rbf, nbr, W_edge, node, n_edges);
  }

  const int mlp_blocks = (num_atoms + MLP_ROWS - 1) / MLP_ROWS;
  mlp_kernel<<<mlp_blocks, 256, 0, stream>>>(node, W1, b1, W2, b2, W3, b3, Wf,
                                             out, num_atoms);
}